// Round 1
// 24129.047 us; speedup vs baseline: 1.1619x; 1.1619x over previous
//
#include <hip/hip_runtime.h>
#include <hip/hip_cooperative_groups.h>
#include <math.h>

namespace cg = cooperative_groups;

#define BB 32
#define HH 1024
#define EE 512
#define TT 63      // T-1
#define SS 64
#define VV 32000

// ---------------------------------------------------------------------------
// Scratch layout inside d_out (floats). d_out is 2016*32000 = 64.5M floats;
// we use ~37.8M as scratch during the recurrence, then gen_gemm overwrites all.
static const size_t OWT0 = 0;                 // [2560][4096] transposed layer0 gates
static const size_t OWT1 = 10485760;          // [2048][4096] transposed layer1 gates
static const size_t OWLT = 18874368;          // [2048][1024] transposed out-linear
static const size_t OXC0 = 20971520;          // [64][32][2560] layer0 input concat
static const size_t OXC1 = 26214400;          // [64][32][2048] layer1 input concat
static const size_t OGP  = 30408704;          // [32][32][4096] gate partials
static const size_t OOP  = 34603008;          // [32][32][1024] out-linear partials
static const size_t OPE  = 35651584;          // [2048][1024] projected encoder (Wa-folded)
static const size_t OCB  = 37748736;          // [2048] ba . x_enc

// ---------------------------------------------------------------------------
__device__ __forceinline__ void fma4(float4& a, float s, const float4 w) {
    a.x = fmaf(s, w.x, a.x);
    a.y = fmaf(s, w.y, a.y);
    a.z = fmaf(s, w.z, a.z);
    a.w = fmaf(s, w.w, a.w);
}

// ---------------------------------------------------------------------------
// Partial GEMM: P[ks][b][r] = sum_{k in slice ks} X[b][k] * W[k][r]
// W transposed layout [K][WPITCH]; 32 k-slices across (block kg) x ...
// Block unit = (rt, kg): rt in [0,NRT) covers 256 r each, kg in [0,32).
// Wave w handles batches [8w, 8w+8); lane owns 4 consecutive r (float4).
// Weights are read exactly once per step (shared across all 32 batches).
template<int WPITCH, int NRT>
__device__ __forceinline__ void pgemm(const float* __restrict__ W,
                                      const float* __restrict__ X, int xpitch,
                                      int kslice, float* __restrict__ P)
{
    const int tid = threadIdx.x, lane = tid & 63, wv = tid >> 6;
    const int nU = NRT * 32;
    for (int u = blockIdx.x; u < nU; u += gridDim.x) {
        const int rt = u >> 5, kg = u & 31;
        const int r0 = rt * 256 + lane * 4;
        const int b0 = wv * 8;
        const int kbase = kg * kslice;
        const float* wb = W + (size_t)kbase * WPITCH + r0;
        const float* xb = X + (size_t)b0 * xpitch + kbase;
        float4 acc[8];
        #pragma unroll
        for (int i = 0; i < 8; ++i) acc[i] = make_float4(0.f, 0.f, 0.f, 0.f);
        #pragma unroll 2
        for (int kk = 0; kk < kslice; kk += 4) {
            float4 w0 = *(const float4*)(wb + (size_t)(kk + 0) * WPITCH);
            float4 w1 = *(const float4*)(wb + (size_t)(kk + 1) * WPITCH);
            float4 w2 = *(const float4*)(wb + (size_t)(kk + 2) * WPITCH);
            float4 w3 = *(const float4*)(wb + (size_t)(kk + 3) * WPITCH);
            #pragma unroll
            for (int i = 0; i < 8; ++i) {
                float4 xv = *(const float4*)(xb + (size_t)i * xpitch + kk);
                fma4(acc[i], xv.x, w0);
                fma4(acc[i], xv.y, w1);
                fma4(acc[i], xv.z, w2);
                fma4(acc[i], xv.w, w3);
            }
        }
        float* pp = P + ((size_t)kg * BB + b0) * WPITCH + r0;
        #pragma unroll
        for (int i = 0; i < 8; ++i) *(float4*)(pp + (size_t)i * WPITCH) = acc[i];
    }
}

// ---------------------------------------------------------------------------
// LSTM finalize: sum 32 k-slice partials, add biases, apply cell update.
// Unit = (b, hc): 64 h values. Wave = gate. h/c written; h duplicated into the
// two consumers' concat buffers.
__device__ __forceinline__ void lstm_fin(const float* __restrict__ P,
    const float* __restrict__ bih, const float* __restrict__ bhh,
    float* __restrict__ cst,
    float* __restrict__ hA, int pA, int oA,
    float* __restrict__ hB, int pB, int oB,
    float* __restrict__ smem)
{
    const int tid = threadIdx.x, lane = tid & 63, g = tid >> 6;
    for (int u = blockIdx.x; u < 512; u += gridDim.x) {
        const int b = u >> 4, hc = u & 15;
        const int h = hc * 64 + lane;
        float s = 0.f;
        #pragma unroll
        for (int sl = 0; sl < 32; ++sl)
            s += P[((size_t)sl * BB + b) * 4096 + g * 1024 + h];
        s += bih[g * 1024 + h] + bhh[g * 1024 + h];
        smem[g * 64 + lane] = s;
        __syncthreads();
        if (tid < 64) {
            float gi = smem[lane], gf = smem[64 + lane];
            float gg = smem[128 + lane], go = smem[192 + lane];
            float si = 1.f / (1.f + expf(-gi));
            float sf = 1.f / (1.f + expf(-gf));
            float so = 1.f / (1.f + expf(-go));
            float cp = cst[(size_t)b * 1024 + h];
            float cn = sf * cp + si * tanhf(gg);
            float hn = so * tanhf(cn);
            cst[(size_t)b * 1024 + h] = cn;
            hA[(size_t)b * pA + oA + h] = hn;
            hB[(size_t)b * pB + oB + h] = hn;
        }
        __syncthreads();
    }
}

// ---------------------------------------------------------------------------
// Attention: scores via precomputed projenc (s = z . projenc[b][j] + cb[b][j]),
// softmax over 64, ctx written into zc[b][1024:2048]. One unit per batch.
__device__ __forceinline__ void attn_phase(const float* __restrict__ xenc,
    const float* __restrict__ pe, const float* __restrict__ cb,
    float* __restrict__ zc, float* __restrict__ smem)
{
    const int tid = threadIdx.x;
    float* zl = smem;          // 1024
    float* pp = smem + 1024;   // 256
    float* wt = smem + 1280;   // 64
    for (int u = blockIdx.x; u < 32; u += gridDim.x) {
        const int b = u;
        for (int i = tid; i < 1024; i += 256) zl[i] = zc[(size_t)b * 2048 + i];
        __syncthreads();
        {
            const int j = tid >> 2, part = tid & 3;
            const float* per = pe + ((size_t)b * 64 + j) * 1024 + part * 256;
            const float* zp = zl + part * 256;
            float p0 = 0.f, p1 = 0.f, p2 = 0.f, p3 = 0.f;
            for (int k = 0; k < 256; k += 4) {
                p0 = fmaf(zp[k], per[k], p0);
                p1 = fmaf(zp[k + 1], per[k + 1], p1);
                p2 = fmaf(zp[k + 2], per[k + 2], p2);
                p3 = fmaf(zp[k + 3], per[k + 3], p3);
            }
            pp[tid] = (p0 + p1) + (p2 + p3);
        }
        __syncthreads();
        if (tid < 64) {
            float sc = pp[tid * 4] + pp[tid * 4 + 1] + pp[tid * 4 + 2] + pp[tid * 4 + 3]
                     + cb[b * 64 + tid];
            float m = sc;
            #pragma unroll
            for (int off = 32; off; off >>= 1) m = fmaxf(m, __shfl_xor(m, off));
            float e = expf(sc - m);
            float ss = e;
            #pragma unroll
            for (int off = 32; off; off >>= 1) ss += __shfl_xor(ss, off);
            wt[tid] = e / ss;
        }
        __syncthreads();
        for (int k = tid; k < 1024; k += 256) {
            float a = 0.f;
            const float* xe = xenc + (size_t)b * (SS * HH) + k;
            #pragma unroll 8
            for (int j = 0; j < SS; ++j) a = fmaf(wt[j], xe[(size_t)j * HH], a);
            zc[(size_t)b * 2048 + 1024 + k] = a;
        }
        __syncthreads();
    }
}

// ---------------------------------------------------------------------------
// Out-linear finalize: sum 32 partials + bias + tanh; write outs[t] and next
// step's layer0 concat slot.
__device__ __forceinline__ void out_fin(const float* __restrict__ P,
    const float* __restrict__ bl, float* __restrict__ outs_t,
    float* __restrict__ xc0n, float* __restrict__ smem)
{
    const int tid = threadIdx.x, lane = tid & 63, wv = tid >> 6;
    for (int u = blockIdx.x; u < 512; u += gridDim.x) {
        const int b = u >> 4, nc = u & 15;
        const int n = nc * 64 + lane;
        float s = 0.f;
        #pragma unroll
        for (int q = 0; q < 8; ++q)
            s += P[((size_t)(wv * 8 + q) * BB + b) * 1024 + n];
        smem[wv * 64 + lane] = s;
        __syncthreads();
        if (tid < 64) {
            float tot = smem[lane] + smem[64 + lane] + smem[128 + lane]
                      + smem[192 + lane] + bl[n];
            float r = tanhf(tot);
            outs_t[(size_t)b * 1024 + n] = r;
            xc0n[(size_t)b * 2560 + 512 + n] = r;
        }
        __syncthreads();
    }
}

// ---------------------------------------------------------------------------
// Persistent cooperative kernel: whole 63-step recurrence, 7 grid syncs/step.
__global__ __launch_bounds__(256, 2)
void decoder_loop(const float* __restrict__ xenc,
                  const float* __restrict__ bih0, const float* __restrict__ bhh0,
                  const float* __restrict__ bih1, const float* __restrict__ bhh1,
                  const float* __restrict__ bl,
                  float* __restrict__ scratch,
                  float* __restrict__ c_state, float* __restrict__ zc,
                  float* __restrict__ outs)
{
    __shared__ float smem[1344];
    cg::grid_group grid = cg::this_grid();
    const float* WT0 = scratch + OWT0;
    const float* WT1 = scratch + OWT1;
    const float* WlT = scratch + OWLT;
    float* xcat0 = scratch + OXC0;
    float* xcat1 = scratch + OXC1;
    float* gatesP = scratch + OGP;
    float* outP = scratch + OOP;
    const float* pe = scratch + OPE;
    const float* cb = scratch + OCB;

    for (int t = 0; t < TT; ++t) {
        float* xc0t = xcat0 + (size_t)t * BB * 2560;
        float* xc0n = xcat0 + (size_t)(t + 1) * BB * 2560;
        float* xc1t = xcat1 + (size_t)t * BB * 2048;
        float* xc1n = xcat1 + (size_t)(t + 1) * BB * 2048;

        pgemm<4096, 16>(WT0, xc0t, 2560, 80, gatesP);          // layer0 gates
        grid.sync();
        lstm_fin(gatesP, bih0, bhh0, c_state,
                 xc1t, 2048, 0, xc0n, 2560, 1536, smem);
        grid.sync();
        pgemm<4096, 16>(WT1, xc1t, 2048, 64, gatesP);          // layer1 gates
        grid.sync();
        lstm_fin(gatesP, bih1, bhh1, c_state + 32768,
                 zc, 2048, 0, xc1n, 2048, 1024, smem);
        grid.sync();
        attn_phase(xenc, pe, cb, zc, smem);                    // scores+softmax+ctx
        grid.sync();
        pgemm<1024, 4>(WlT, zc, 2048, 64, outP);               // out-linear
        grid.sync();
        out_fin(outP, bl, outs + (size_t)t * BB * HH, xc0n, smem);
        grid.sync();
    }
}

// ---------------------------------------------------------------------------
// Fallback wrappers (used only if cooperative launch is unavailable).
__global__ __launch_bounds__(256, 2)
void k_gate_gemm(const float* __restrict__ W, const float* __restrict__ X,
                 int xpitch, int kslice, float* __restrict__ P)
{ pgemm<4096, 16>(W, X, xpitch, kslice, P); }

__global__ __launch_bounds__(256, 2)
void k_out_gemm(const float* __restrict__ W, const float* __restrict__ X,
                float* __restrict__ P)
{ pgemm<1024, 4>(W, X, 2048, 64, P); }

__global__ __launch_bounds__(256)
void k_lstm_fin(const float* __restrict__ P, const float* __restrict__ bih,
                const float* __restrict__ bhh, float* __restrict__ cst,
                float* __restrict__ hA, int pA, int oA,
                float* __restrict__ hB, int pB, int oB)
{ __shared__ float smem[256]; lstm_fin(P, bih, bhh, cst, hA, pA, oA, hB, pB, oB, smem); }

__global__ __launch_bounds__(256)
void k_attn(const float* __restrict__ xenc, const float* __restrict__ pe,
            const float* __restrict__ cb, float* __restrict__ zc)
{ __shared__ float smem[1344]; attn_phase(xenc, pe, cb, zc, smem); }

__global__ __launch_bounds__(256)
void k_out_fin(const float* __restrict__ P, const float* __restrict__ bl,
               float* __restrict__ outs_t, float* __restrict__ xc0n)
{ __shared__ float smem[256]; out_fin(P, bl, outs_t, xc0n, smem); }

// ---------------------------------------------------------------------------
// Setup kernels
__global__ __launch_bounds__(256)
void init_kernel2(const float* __restrict__ h0, const float* __restrict__ c0,
                  float* __restrict__ c_state, float* __restrict__ xcat0,
                  float* __restrict__ xcat1)
{
    int i = blockIdx.x * 256 + threadIdx.x;   // 0..65535
    c_state[i] = c0[i];
    int b = (i >> 10) & 31, h = i & 1023, l = i >> 15;
    if (l == 0) {
        xcat0[(size_t)b * 2560 + 1536 + h] = h0[i];   // h_prev layer0 @ t=0
        xcat0[(size_t)b * 2560 + 512 + h] = 0.f;      // prev output @ t=0
    } else {
        xcat1[(size_t)b * 2048 + 1024 + h] = h0[i];   // h_prev layer1 @ t=0
    }
}

__global__ __launch_bounds__(128)
void embed_kernel2(const int* __restrict__ x, const float* __restrict__ emb,
                   float* __restrict__ xcat0)
{
    int t = blockIdx.x >> 5, b = blockIdx.x & 31;
    int tok = x[b * 64 + t];
    const float4* src = (const float4*)(emb + (size_t)tok * EE);
    float4* dst = (float4*)(xcat0 + ((size_t)t * BB + b) * 2560);
    dst[threadIdx.x] = src[threadIdx.x];
}

// dst[c * dpitch + r] = src[r * C + c]
__global__ __launch_bounds__(256)
void transpose_kernel(const float* __restrict__ src, int C,
                      float* __restrict__ dst, int dpitch)
{
    __shared__ float tile[32][33];
    const int tx = threadIdx.x & 31, ty = threadIdx.x >> 5;
    const int c0 = blockIdx.x * 32, r0 = blockIdx.y * 32;
    #pragma unroll
    for (int i = 0; i < 32; i += 8)
        tile[ty + i][tx] = src[(size_t)(r0 + ty + i) * C + (c0 + tx)];
    __syncthreads();
    #pragma unroll
    for (int i = 0; i < 32; i += 8)
        dst[(size_t)(c0 + ty + i) * dpitch + (r0 + tx)] = tile[tx][ty + i];
}

// projenc[r][k] = sum_h xenc_flat[r][h] * Wa[h][k]   (t-invariant attn fold)
__global__ __launch_bounds__(256)
void projenc_kernel(const float* __restrict__ xenc, const float* __restrict__ Wa,
                    float* __restrict__ pe)
{
    const int r = blockIdx.x;
    const int n0 = threadIdx.x * 4;
    const float* xe = xenc + (size_t)r * HH;
    float4 a = make_float4(0.f, 0.f, 0.f, 0.f);
    for (int h = 0; h < HH; h += 4) {
        float4 xv = *(const float4*)(xe + h);
        fma4(a, xv.x, *(const float4*)(Wa + (size_t)h * HH + n0));
        fma4(a, xv.y, *(const float4*)(Wa + (size_t)(h + 1) * HH + n0));
        fma4(a, xv.z, *(const float4*)(Wa + (size_t)(h + 2) * HH + n0));
        fma4(a, xv.w, *(const float4*)(Wa + (size_t)(h + 3) * HH + n0));
    }
    *(float4*)(pe + (size_t)r * HH + n0) = a;
}

__global__ __launch_bounds__(64)
void cbias_kernel(const float* __restrict__ xenc, const float* __restrict__ ba,
                  float* __restrict__ cb)
{
    const int r = blockIdx.x;
    const float* xe = xenc + (size_t)r * HH;
    float s = 0.f;
    for (int k = threadIdx.x; k < HH; k += 64) s = fmaf(ba[k], xe[k], s);
    #pragma unroll
    for (int off = 32; off; off >>= 1) s += __shfl_xor(s, off);
    if (threadIdx.x == 0) cb[r] = s;
}

// ---------------------------------------------------------------------------
// generator GEMM (unchanged from baseline)
__global__ __launch_bounds__(256)
void gen_gemm_kernel(const float* __restrict__ outs, const float* __restrict__ Wg,
                     const float* __restrict__ bg, float* __restrict__ out)
{
    __shared__ float As[32 * 68];
    __shared__ float Bs[64 * 68];
    const int tid = threadIdx.x;
    const int tn = tid & 15, tm = tid >> 4;
    const int vbase = blockIdx.x * 64;
    const int rbase = blockIdx.y * 32;
    float acc[2][4] = {};

    const int arow = tid >> 3;
    const int acol = (tid & 7) * 8;
    int rg = rbase + arow;
    int ab = rg / TT, at = rg % TT;
    const float* asrc = outs + ((size_t)at * BB + ab) * HH + acol;
    const int brow = tid >> 2;
    const int bcol = (tid & 3) * 16;
    const float* bsrc = Wg + (size_t)(vbase + brow) * HH + bcol;

    for (int k0 = 0; k0 < HH; k0 += 64) {
        float4 a4a = *(const float4*)(asrc + k0);
        float4 a4b = *(const float4*)(asrc + k0 + 4);
        *(float4*)&As[arow * 68 + acol] = a4a;
        *(float4*)&As[arow * 68 + acol + 4] = a4b;
        float4 q0 = *(const float4*)(bsrc + k0);
        float4 q1 = *(const float4*)(bsrc + k0 + 4);
        float4 q2 = *(const float4*)(bsrc + k0 + 8);
        float4 q3 = *(const float4*)(bsrc + k0 + 12);
        *(float4*)&Bs[brow * 68 + bcol] = q0;
        *(float4*)&Bs[brow * 68 + bcol + 4] = q1;
        *(float4*)&Bs[brow * 68 + bcol + 8] = q2;
        *(float4*)&Bs[brow * 68 + bcol + 12] = q3;
        __syncthreads();
        #pragma unroll
        for (int k = 0; k < 64; k += 4) {
            float4 a0 = *(const float4*)&As[(tm * 2 + 0) * 68 + k];
            float4 a1 = *(const float4*)&As[(tm * 2 + 1) * 68 + k];
            float4 b0 = *(const float4*)&Bs[(tn * 4 + 0) * 68 + k];
            float4 b1 = *(const float4*)&Bs[(tn * 4 + 1) * 68 + k];
            float4 b2 = *(const float4*)&Bs[(tn * 4 + 2) * 68 + k];
            float4 b3 = *(const float4*)&Bs[(tn * 4 + 3) * 68 + k];
            acc[0][0] += a0.x * b0.x + a0.y * b0.y + a0.z * b0.z + a0.w * b0.w;
            acc[0][1] += a0.x * b1.x + a0.y * b1.y + a0.z * b1.z + a0.w * b1.w;
            acc[0][2] += a0.x * b2.x + a0.y * b2.y + a0.z * b2.z + a0.w * b2.w;
            acc[0][3] += a0.x * b3.x + a0.y * b3.y + a0.z * b3.z + a0.w * b3.w;
            acc[1][0] += a1.x * b0.x + a1.y * b0.y + a1.z * b0.z + a1.w * b0.w;
            acc[1][1] += a1.x * b1.x + a1.y * b1.y + a1.z * b1.z + a1.w * b1.w;
            acc[1][2] += a1.x * b2.x + a1.y * b2.y + a1.z * b2.z + a1.w * b2.w;
            acc[1][3] += a1.x * b3.x + a1.y * b3.y + a1.z * b3.z + a1.w * b3.w;
        }
        __syncthreads();
    }
    #pragma unroll
    for (int i = 0; i < 2; ++i) {
        int r = rbase + tm * 2 + i;
        #pragma unroll
        for (int jj = 0; jj < 4; ++jj) {
            int v = vbase + tn * 4 + jj;
            out[(size_t)r * VV + v] = acc[i][jj] + bg[v];
        }
    }
}

// ---------------------------------------------------------------------------
__global__ __launch_bounds__(256)
void logsoftmax_kernel(float* __restrict__ out)
{
    __shared__ float red[4];
    __shared__ float red2[4];
    const int tid = threadIdx.x;
    float* row = out + (size_t)blockIdx.x * VV;
    float m = -1e30f;
    for (int i = tid; i < VV; i += 256) m = fmaxf(m, row[i]);
    for (int off = 32; off; off >>= 1) m = fmaxf(m, __shfl_xor(m, off));
    if ((tid & 63) == 0) red[tid >> 6] = m;
    __syncthreads();
    m = fmaxf(fmaxf(red[0], red[1]), fmaxf(red[2], red[3]));
    float s = 0.f;
    for (int i = tid; i < VV; i += 256) s += expf(row[i] - m);
    for (int off = 32; off; off >>= 1) s += __shfl_xor(s, off);
    if ((tid & 63) == 0) red2[tid >> 6] = s;
    __syncthreads();
    s = red2[0] + red2[1] + red2[2] + red2[3];
    float lse = m + logf(s);
    for (int i = tid; i < VV; i += 256) row[i] = row[i] - lse;
}

// ---------------------------------------------------------------------------
extern "C" void kernel_launch(void* const* d_in, const int* in_sizes, int n_in,
                              void* d_out, int out_size, void* d_ws, size_t ws_size,
                              hipStream_t stream)
{
    (void)in_sizes; (void)n_in; (void)out_size; (void)ws_size;
    const int*   x    = (const int*)  d_in[0];
    const float* h0   = (const float*)d_in[1];
    const float* c0   = (const float*)d_in[2];
    const float* x_enc= (const float*)d_in[3];
    const float* emb  = (const float*)d_in[4];
    const float* Wih0 = (const float*)d_in[5];
    const float* Whh0 = (const float*)d_in[6];
    const float* bih0 = (const float*)d_in[7];
    const float* bhh0 = (const float*)d_in[8];
    const float* Wih1 = (const float*)d_in[9];
    const float* Whh1 = (const float*)d_in[10];
    const float* bih1 = (const float*)d_in[11];
    const float* bhh1 = (const float*)d_in[12];
    const float* Wa   = (const float*)d_in[13];
    const float* ba   = (const float*)d_in[14];
    const float* Wl   = (const float*)d_in[15];
    const float* bl   = (const float*)d_in[16];
    const float* Wg   = (const float*)d_in[17];
    const float* bg   = (const float*)d_in[18];
    float* out = (float*)d_out;
    float* scratch = (float*)d_out;     // scratch region; overwritten by gen_gemm at end

    // ws layout
    float* ws      = (float*)d_ws;
    float* c_state = ws;                  // [2][32][1024]
    float* zc      = ws + 65536;          // [32][2048]  (z | ctx)
    float* outs    = ws + 131072;         // [63][32][1024]

    // ---- setup: state init, embedding gather, weight transposes, attn fold
    init_kernel2<<<256, 256, 0, stream>>>(h0, c0, c_state,
                                          scratch + OXC0, scratch + OXC1);
    embed_kernel2<<<TT * BB, 128, 0, stream>>>(x, emb, scratch + OXC0);
    transpose_kernel<<<dim3(48, 128), 256, 0, stream>>>(Wih0, 1536, scratch + OWT0, 4096);
    transpose_kernel<<<dim3(32, 128), 256, 0, stream>>>(Whh0, 1024,
                         scratch + OWT0 + (size_t)1536 * 4096, 4096);
    transpose_kernel<<<dim3(32, 128), 256, 0, stream>>>(Wih1, 1024, scratch + OWT1, 4096);
    transpose_kernel<<<dim3(32, 128), 256, 0, stream>>>(Whh1, 1024,
                         scratch + OWT1 + (size_t)1024 * 4096, 4096);
    transpose_kernel<<<dim3(64, 32), 256, 0, stream>>>(Wl, 2048, scratch + OWLT, 1024);
    projenc_kernel<<<2048, 256, 0, stream>>>(x_enc, Wa, scratch + OPE);
    cbias_kernel<<<2048, 64, 0, stream>>>(x_enc, ba, scratch + OCB);

    // ---- main recurrence: persistent cooperative kernel if available
    static int coopGrid = -2;
    if (coopGrid == -2) {
        int dev = 0; hipGetDevice(&dev);
        int coop = 0;
        hipDeviceGetAttribute(&coop, hipDeviceAttributeCooperativeLaunch, dev);
        if (!coop) coopGrid = 0;
        else {
            int occ = 0;
            if (hipOccupancyMaxActiveBlocksPerMultiprocessor(&occ, decoder_loop,
                    256, 0) != hipSuccess || occ < 1) occ = 0;
            int nCU = 256;
            hipDeviceProp_t prop;
            if (hipGetDeviceProperties(&prop, dev) == hipSuccess && prop.multiProcessorCount > 0)
                nCU = prop.multiProcessorCount;
            int g = occ * nCU;
            if (g > 512) g = 512;
            coopGrid = g;
        }
    }

    bool done = false;
    if (coopGrid > 0) {
        void* args[] = {(void*)&x_enc, (void*)&bih0, (void*)&bhh0, (void*)&bih1,
                        (void*)&bhh1, (void*)&bl, (void*)&scratch, (void*)&c_state,
                        (void*)&zc, (void*)&outs};
        hipError_t e = hipLaunchCooperativeKernel(decoder_loop, dim3(coopGrid),
                                                  dim3(256), args, 0u, stream);
        if (e == hipSuccess) done = true;
        else coopGrid = 0;   // don't retry
    }
    if (!done) {
        // fallback: same phases as separate launches
        for (int t = 0; t < TT; ++t) {
            float* xc0t = scratch + OXC0 + (size_t)t * BB * 2560;
            float* xc0n = scratch + OXC0 + (size_t)(t + 1) * BB * 2560;
            float* xc1t = scratch + OXC1 + (size_t)t * BB * 2048;
            float* xc1n = scratch + OXC1 + (size_t)(t + 1) * BB * 2048;
            k_gate_gemm<<<512, 256, 0, stream>>>(scratch + OWT0, xc0t, 2560, 80, scratch + OGP);
            k_lstm_fin<<<512, 256, 0, stream>>>(scratch + OGP, bih0, bhh0, c_state,
                                                xc1t, 2048, 0, xc0n, 2560, 1536);
            k_gate_gemm<<<512, 256, 0, stream>>>(scratch + OWT1, xc1t, 2048, 64, scratch + OGP);
            k_lstm_fin<<<512, 256, 0, stream>>>(scratch + OGP, bih1, bhh1, c_state + 32768,
                                                zc, 2048, 0, xc1n, 2048, 1024);
            k_attn<<<32, 256, 0, stream>>>(x_enc, scratch + OPE, scratch + OCB, zc);
            k_out_gemm<<<128, 256, 0, stream>>>(scratch + OWLT, zc, scratch + OOP);
            k_out_fin<<<512, 256, 0, stream>>>(scratch + OOP, bl,
                                               outs + (size_t)t * BB * HH, xc0n);
        }
    }

    // ---- generator + log-softmax (overwrite d_out with final result)
    gen_gemm_kernel<<<dim3(VV / 64, 2016 / 32), 256, 0, stream>>>(outs, Wg, bg, out);
    logsoftmax_kernel<<<2016, 256, 0, stream>>>(out);
}

// Round 2
// 22596.362 us; speedup vs baseline: 1.2407x; 1.0678x over previous
//
#include <hip/hip_runtime.h>
#include <math.h>

#define BB 32
#define HH 1024
#define EE 512
#define TT 63      // T-1
#define SS 64
#define VV 32000

// ---------------------------------------------------------------------------
// Scratch layout inside d_out (floats). All recurrence buffers are per-t slots
// so every cross-block-communicated address is written-then-read exactly once
// per launch (virgin-address rule: producers write-through via agent-scope
// atomic stores; consumers' first plain read misses L2 and hits the coherent
// point). gen_gemm overwrites d_out at the end.
#define OXC0 0u           // [64][32][2560]  layer0 input concat (emb|prev|h0_prev)
#define OXC1 5242880u     // [64][32][2048]  layer1 input concat (h0_new|h1_prev)
#define OZC  9437184u     // [63][32][2048]  (z | ctx) per step
#define OPE  13565952u    // [2048][1024]    projected encoder (Wa folded)
#define OCB  15663104u    // [2048]          ba . x_enc

// ws layout (floats): c_state[2][32][1024] @0 ; outs[63][32][1024] @65536 ;
// barrier flags (uint) @2129920
#define WS_OUTS  65536u
#define WS_FLAGS 2129920u

// ---------------------------------------------------------------------------
__device__ __forceinline__ void st_dev(float* p, float v) {
    __hip_atomic_store(p, v, __ATOMIC_RELAXED, __HIP_MEMORY_SCOPE_AGENT);
}
__device__ __forceinline__ float ld_dev(const float* p) {
    return __hip_atomic_load(p, __ATOMIC_RELAXED, __HIP_MEMORY_SCOPE_AGENT);
}

// Custom global barrier: monotonic counter + generation flag, agent-scope
// relaxed atomics only — NO L2 writeback/invalidate (unlike cg grid.sync).
// Data visibility: producers used write-through atomic stores and
// __syncthreads() (below) drains vmcnt before the arrive.
__device__ __forceinline__ void gbar(unsigned* flags, int nblk, unsigned idx)
{
    __syncthreads();   // drains vmcnt/lgkmcnt for whole block
    if (threadIdx.x == 0) {
        unsigned* ctr = flags;
        unsigned* gen = flags + 32;   // separate 128B line
        unsigned old = __hip_atomic_fetch_add(ctr, 1u, __ATOMIC_RELAXED,
                                              __HIP_MEMORY_SCOPE_AGENT);
        unsigned want = idx + 1u;
        if (old == want * (unsigned)nblk - 1u) {
            __hip_atomic_store(gen, want, __ATOMIC_RELAXED, __HIP_MEMORY_SCOPE_AGENT);
        } else {
            while (__hip_atomic_load(gen, __ATOMIC_RELAXED,
                                     __HIP_MEMORY_SCOPE_AGENT) < want)
                __builtin_amdgcn_s_sleep(8);
        }
    }
    __syncthreads();   // also a compiler memory barrier: no load hoisting above
}

// ---------------------------------------------------------------------------
// Fused gates-GEMM + LSTM cell for one layer, one step. Full K per block:
// unit u covers 2 h-values x 32 batches (all 4 gates). Thread=(b,hl,gate),
// one K-long dot with 4 independent FMA chains (float4 acc). x staged in LDS
// with rotated conflict-free float4 layout; weights read in original
// row-major [4H][K] layout, 2 distinct addrs per wave (L1 broadcast).
__device__ void lstm_phase(const float* __restrict__ Wx, int K1,
                           const float* __restrict__ Wh,
                           const float* __restrict__ bih, const float* __restrict__ bhh,
                           const float* __restrict__ xc, int xpitch,
                           float* __restrict__ cst,
                           float* dA, int pA, int oA,
                           float* dB, int pB, int oB,
                           float* smem, int nblk)
{
    float4* lds4 = (float4*)smem;          // 64 kq x 32 rotated slots = 32 KB
    float* gx = smem + 8192;               // 256 floats gate exchange
    const int tid = threadIdx.x;
    const int b = tid & 31, hl = (tid >> 5) & 1, gate = tid >> 6;
    const int K = K1 + HH;
    for (int u = blockIdx.x; u < 512; u += nblk) {
        const int h = u * 2 + hl;
        const int row = gate * HH + h;
        float4 acc = make_float4(0.f, 0.f, 0.f, 0.f);
        for (int c = 0; c < K / 256; ++c) {
            const int k0 = c * 256;
            __syncthreads();
            #pragma unroll
            for (int i = 0; i < 8; ++i) {
                int idx = tid + i * 256;
                int bb = idx >> 6, kq = idx & 63;
                float4 v = *(const float4*)(xc + (size_t)bb * xpitch + k0 + kq * 4);
                lds4[kq * 32 + ((bb + kq) & 31)] = v;
            }
            __syncthreads();
            const float* wr = (k0 < K1) ? Wx + (size_t)row * K1 + k0
                                        : Wh + (size_t)row * HH + (k0 - K1);
            #pragma unroll 8
            for (int k = 0; k < 256; k += 4) {
                const int kq = k >> 2;
                float4 w4 = *(const float4*)(wr + k);
                float4 xq = lds4[kq * 32 + ((b + kq) & 31)];
                acc.x = fmaf(xq.x, w4.x, acc.x);
                acc.y = fmaf(xq.y, w4.y, acc.y);
                acc.z = fmaf(xq.z, w4.z, acc.z);
                acc.w = fmaf(xq.w, w4.w, acc.w);
            }
        }
        float d = (acc.x + acc.y) + (acc.z + acc.w) + bih[row] + bhh[row];
        __syncthreads();
        gx[gate * 64 + hl * 32 + b] = d;
        __syncthreads();
        if (tid < 64) {   // gate==0 threads own (b,hl)
            float gi = gx[tid], gf = gx[64 + tid];
            float gg = gx[128 + tid], go = gx[192 + tid];
            float si = 1.f / (1.f + expf(-gi));
            float sf = 1.f / (1.f + expf(-gf));
            float so = 1.f / (1.f + expf(-go));
            float cp = ld_dev(cst + (size_t)b * HH + h);
            float cn = sf * cp + si * tanhf(gg);
            float hn = so * tanhf(cn);
            st_dev(cst + (size_t)b * HH + h, cn);
            st_dev(dA + (size_t)b * pA + oA + h, hn);
            st_dev(dB + (size_t)b * pB + oB + h, hn);
        }
    }
}

// ---------------------------------------------------------------------------
// Out-linear: out[b][n] = tanh(zc[b] . Wl[n] + bl[n]); K=2048 split 4-ways per
// thread within each LDS chunk, LDS-reduced. Writes outs[t] and next step's
// prev-out slot.
__device__ void outlin_phase(const float* __restrict__ Wl, const float* __restrict__ bl,
                             const float* __restrict__ zc,
                             float* __restrict__ outs_t, float* __restrict__ xc0n,
                             float* smem, int nblk)
{
    float4* lds4 = (float4*)smem;
    float* gx = smem + 8192;
    const int tid = threadIdx.x;
    const int b = tid & 31, nl = (tid >> 5) & 1, q = tid >> 6;
    for (int u = blockIdx.x; u < 512; u += nblk) {
        const int n = u * 2 + nl;
        float4 acc = make_float4(0.f, 0.f, 0.f, 0.f);
        for (int c = 0; c < 8; ++c) {
            const int k0 = c * 256;
            __syncthreads();
            #pragma unroll
            for (int i = 0; i < 8; ++i) {
                int idx = tid + i * 256;
                int bb = idx >> 6, kq = idx & 63;
                float4 v = *(const float4*)(zc + (size_t)bb * 2048 + k0 + kq * 4);
                lds4[kq * 32 + ((bb + kq) & 31)] = v;
            }
            __syncthreads();
            const float* wr = Wl + (size_t)n * 2048 + k0 + q * 64;
            #pragma unroll
            for (int k = 0; k < 64; k += 4) {
                const int kq = (q * 64 + k) >> 2;
                float4 w4 = *(const float4*)(wr + k);
                float4 xq = lds4[kq * 32 + ((b + kq) & 31)];
                acc.x = fmaf(xq.x, w4.x, acc.x);
                acc.y = fmaf(xq.y, w4.y, acc.y);
                acc.z = fmaf(xq.z, w4.z, acc.z);
                acc.w = fmaf(xq.w, w4.w, acc.w);
            }
        }
        float part = (acc.x + acc.y) + (acc.z + acc.w);
        __syncthreads();
        gx[q * 64 + nl * 32 + b] = part;
        __syncthreads();
        if (tid < 64) {   // q==0 threads own (b,nl)
            float tot = gx[tid] + gx[64 + tid] + gx[128 + tid] + gx[192 + tid] + bl[n];
            float r = tanhf(tot);
            st_dev(outs_t + (size_t)b * HH + n, r);
            st_dev(xc0n + (size_t)b * 2560 + 512 + n, r);
        }
    }
}

// ---------------------------------------------------------------------------
// Attention via t-invariant projected encoder: s_j = z.pe[b][j] + cb[b][j],
// softmax over 64, ctx into zc[b][1024:2048]. One block per batch.
__device__ void attn_phase(const float* __restrict__ xenc, const float* __restrict__ pe,
                           const float* __restrict__ cb, float* __restrict__ zc,
                           float* smem, int nblk)
{
    float* zl = smem;          // 1024
    float* pp = smem + 1024;   // 256
    float* wt = smem + 1280;   // 64
    const int tid = threadIdx.x;
    for (int u = blockIdx.x; u < 32; u += nblk) {
        const int b = u;
        __syncthreads();
        for (int i = tid; i < 1024; i += 256) zl[i] = zc[(size_t)b * 2048 + i];
        __syncthreads();
        {
            const int j = tid >> 2, part = tid & 3;
            const float* per = pe + ((size_t)b * 64 + j) * 1024 + part * 256;
            const float* zp = zl + part * 256;
            float p0 = 0.f, p1 = 0.f, p2 = 0.f, p3 = 0.f;
            for (int k = 0; k < 256; k += 4) {
                p0 = fmaf(zp[k], per[k], p0);
                p1 = fmaf(zp[k + 1], per[k + 1], p1);
                p2 = fmaf(zp[k + 2], per[k + 2], p2);
                p3 = fmaf(zp[k + 3], per[k + 3], p3);
            }
            pp[tid] = (p0 + p1) + (p2 + p3);
        }
        __syncthreads();
        if (tid < 64) {
            float sc = pp[tid * 4] + pp[tid * 4 + 1] + pp[tid * 4 + 2] + pp[tid * 4 + 3]
                     + cb[b * 64 + tid];
            float m = sc;
            #pragma unroll
            for (int off = 32; off; off >>= 1) m = fmaxf(m, __shfl_xor(m, off));
            float e = expf(sc - m);
            float ss = e;
            #pragma unroll
            for (int off = 32; off; off >>= 1) ss += __shfl_xor(ss, off);
            wt[tid] = e / ss;
        }
        __syncthreads();
        for (int k = tid; k < 1024; k += 256) {
            float a = 0.f;
            const float* xe = xenc + (size_t)b * (SS * HH) + k;
            #pragma unroll 8
            for (int j = 0; j < SS; ++j) a = fmaf(wt[j], xe[(size_t)j * HH], a);
            st_dev(zc + (size_t)b * 2048 + 1024 + k, a);
        }
        __syncthreads();
    }
}

// ---------------------------------------------------------------------------
// Persistent kernel: whole 63-step recurrence, 4 custom barriers/step.
// Launched cooperatively ONLY for the co-residency guarantee; never cg-syncs.
__global__ __launch_bounds__(256, 2)
void decoder_loop(const float* __restrict__ Wih0, const float* __restrict__ Whh0,
                  const float* __restrict__ bih0, const float* __restrict__ bhh0,
                  const float* __restrict__ Wih1, const float* __restrict__ Whh1,
                  const float* __restrict__ bih1, const float* __restrict__ bhh1,
                  const float* __restrict__ Wl, const float* __restrict__ bl,
                  const float* __restrict__ xenc,
                  float* __restrict__ scratch, float* __restrict__ cst,
                  float* __restrict__ outs, unsigned* __restrict__ flags)
{
    __shared__ __align__(16) float smem[8448];
    const int nblk = gridDim.x;
    float* xc0 = scratch + OXC0;
    float* xc1 = scratch + OXC1;
    float* zct = scratch + OZC;
    const float* pe = scratch + OPE;
    const float* cb = scratch + OCB;
    unsigned bi = 0;
    for (int t = 0; t < TT; ++t) {
        float* xc0t = xc0 + (size_t)t * BB * 2560;
        float* xc0n = xc0 + (size_t)(t + 1) * BB * 2560;
        float* xc1t = xc1 + (size_t)t * BB * 2048;
        float* xc1n = xc1 + (size_t)(t + 1) * BB * 2048;
        float* zc   = zct + (size_t)t * BB * 2048;

        lstm_phase(Wih0, 1536, Whh0, bih0, bhh0, xc0t, 2560, cst,
                   xc1t, 2048, 0, xc0n, 2560, 1536, smem, nblk);
        gbar(flags, nblk, bi++);
        lstm_phase(Wih1, 1024, Whh1, bih1, bhh1, xc1t, 2048, cst + 32768,
                   zc, 2048, 0, xc1n, 2048, 1024, smem, nblk);
        gbar(flags, nblk, bi++);
        attn_phase(xenc, pe, cb, zc, smem, nblk);
        gbar(flags, nblk, bi++);
        outlin_phase(Wl, bl, zc, outs + (size_t)t * BB * HH, xc0n, smem, nblk);
        gbar(flags, nblk, bi++);
    }
}

// ---------------------------------------------------------------------------
// Fallback wrappers (used only if cooperative launch is unavailable):
// same phases as 4 separate launches per step (kernel boundaries = coherence).
__global__ __launch_bounds__(256, 2)
void k_lstm(const float* Wx, int K1, const float* Wh,
            const float* bih, const float* bhh,
            const float* xc, int xpitch, float* cst,
            float* dA, int pA, int oA, float* dB, int pB, int oB)
{
    __shared__ __align__(16) float smem[8448];
    lstm_phase(Wx, K1, Wh, bih, bhh, xc, xpitch, cst, dA, pA, oA, dB, pB, oB,
               smem, gridDim.x);
}
__global__ __launch_bounds__(256, 2)
void k_attn(const float* xenc, const float* pe, const float* cb, float* zc)
{
    __shared__ __align__(16) float smem[8448];
    attn_phase(xenc, pe, cb, zc, smem, gridDim.x);
}
__global__ __launch_bounds__(256, 2)
void k_outlin(const float* Wl, const float* bl, const float* zc,
              float* outs_t, float* xc0n)
{
    __shared__ __align__(16) float smem[8448];
    outlin_phase(Wl, bl, zc, outs_t, xc0n, smem, gridDim.x);
}

// ---------------------------------------------------------------------------
// Setup kernels
__global__ __launch_bounds__(256)
void init_kernel2(const float* __restrict__ h0, const float* __restrict__ c0,
                  float* __restrict__ cst, float* __restrict__ xc0,
                  float* __restrict__ xc1, unsigned* __restrict__ flags)
{
    int i = blockIdx.x * 256 + threadIdx.x;   // 0..65535
    cst[i] = c0[i];
    int l = i >> 15, b = (i >> 10) & 31, h = i & 1023;
    if (l == 0) {
        xc0[(size_t)b * 2560 + 1536 + h] = h0[i];   // h_prev layer0 @ t=0
        xc0[(size_t)b * 2560 + 512 + h] = 0.f;      // prev output @ t=0
    } else {
        xc1[(size_t)b * 2048 + 1024 + h] = h0[i];   // h_prev layer1 @ t=0
    }
    if (i < 64) flags[i] = 0u;                      // barrier ctr/gen
}

__global__ __launch_bounds__(128)
void embed_kernel2(const int* __restrict__ x, const float* __restrict__ emb,
                   float* __restrict__ xc0)
{
    int t = blockIdx.x >> 5, b = blockIdx.x & 31;
    int tok = x[b * 64 + t];
    const float4* src = (const float4*)(emb + (size_t)tok * EE);
    float4* dst = (float4*)(xc0 + ((size_t)t * BB + b) * 2560);
    dst[threadIdx.x] = src[threadIdx.x];
}

__device__ __forceinline__ void fma4h(float4& a, float s, const float4 w) {
    a.x = fmaf(s, w.x, a.x); a.y = fmaf(s, w.y, a.y);
    a.z = fmaf(s, w.z, a.z); a.w = fmaf(s, w.w, a.w);
}

// pe[r][n] = sum_h xenc_flat[r][h] * Wa[h][n]   (t-invariant attention fold)
__global__ __launch_bounds__(256)
void projenc_kernel(const float* __restrict__ xenc, const float* __restrict__ Wa,
                    float* __restrict__ pe)
{
    const int r = blockIdx.x;
    const int n0 = threadIdx.x * 4;
    const float* xe = xenc + (size_t)r * HH;
    float4 a = make_float4(0.f, 0.f, 0.f, 0.f);
    for (int h = 0; h < HH; h += 4) {
        float4 xv = *(const float4*)(xe + h);
        fma4h(a, xv.x, *(const float4*)(Wa + (size_t)h * HH + n0));
        fma4h(a, xv.y, *(const float4*)(Wa + (size_t)(h + 1) * HH + n0));
        fma4h(a, xv.z, *(const float4*)(Wa + (size_t)(h + 2) * HH + n0));
        fma4h(a, xv.w, *(const float4*)(Wa + (size_t)(h + 3) * HH + n0));
    }
    *(float4*)(pe + (size_t)r * HH + n0) = a;
}

__global__ __launch_bounds__(64)
void cbias_kernel(const float* __restrict__ xenc, const float* __restrict__ ba,
                  float* __restrict__ cb)
{
    const int r = blockIdx.x;
    const float* xe = xenc + (size_t)r * HH;
    float s = 0.f;
    for (int k = threadIdx.x; k < HH; k += 64) s = fmaf(ba[k], xe[k], s);
    #pragma unroll
    for (int off = 32; off; off >>= 1) s += __shfl_xor(s, off);
    if (threadIdx.x == 0) cb[r] = s;
}

// ---------------------------------------------------------------------------
// generator GEMM (unchanged)
__global__ __launch_bounds__(256)
void gen_gemm_kernel(const float* __restrict__ outs, const float* __restrict__ Wg,
                     const float* __restrict__ bg, float* __restrict__ out)
{
    __shared__ float As[32 * 68];
    __shared__ float Bs[64 * 68];
    const int tid = threadIdx.x;
    const int tn = tid & 15, tm = tid >> 4;
    const int vbase = blockIdx.x * 64;
    const int rbase = blockIdx.y * 32;
    float acc[2][4] = {};

    const int arow = tid >> 3;
    const int acol = (tid & 7) * 8;
    int rg = rbase + arow;
    int ab = rg / TT, at = rg % TT;
    const float* asrc = outs + ((size_t)at * BB + ab) * HH + acol;
    const int brow = tid >> 2;
    const int bcol = (tid & 3) * 16;
    const float* bsrc = Wg + (size_t)(vbase + brow) * HH + bcol;

    for (int k0 = 0; k0 < HH; k0 += 64) {
        float4 a4a = *(const float4*)(asrc + k0);
        float4 a4b = *(const float4*)(asrc + k0 + 4);
        *(float4*)&As[arow * 68 + acol] = a4a;
        *(float4*)&As[arow * 68 + acol + 4] = a4b;
        float4 q0 = *(const float4*)(bsrc + k0);
        float4 q1 = *(const float4*)(bsrc + k0 + 4);
        float4 q2 = *(const float4*)(bsrc + k0 + 8);
        float4 q3 = *(const float4*)(bsrc + k0 + 12);
        *(float4*)&Bs[brow * 68 + bcol] = q0;
        *(float4*)&Bs[brow * 68 + bcol + 4] = q1;
        *(float4*)&Bs[brow * 68 + bcol + 8] = q2;
        *(float4*)&Bs[brow * 68 + bcol + 12] = q3;
        __syncthreads();
        #pragma unroll
        for (int k = 0; k < 64; k += 4) {
            float4 a0 = *(const float4*)&As[(tm * 2 + 0) * 68 + k];
            float4 a1 = *(const float4*)&As[(tm * 2 + 1) * 68 + k];
            float4 b0 = *(const float4*)&Bs[(tn * 4 + 0) * 68 + k];
            float4 b1 = *(const float4*)&Bs[(tn * 4 + 1) * 68 + k];
            float4 b2 = *(const float4*)&Bs[(tn * 4 + 2) * 68 + k];
            float4 b3 = *(const float4*)&Bs[(tn * 4 + 3) * 68 + k];
            acc[0][0] += a0.x * b0.x + a0.y * b0.y + a0.z * b0.z + a0.w * b0.w;
            acc[0][1] += a0.x * b1.x + a0.y * b1.y + a0.z * b1.z + a0.w * b1.w;
            acc[0][2] += a0.x * b2.x + a0.y * b2.y + a0.z * b2.z + a0.w * b2.w;
            acc[0][3] += a0.x * b3.x + a0.y * b3.y + a0.z * b3.z + a0.w * b3.w;
            acc[1][0] += a1.x * b0.x + a1.y * b0.y + a1.z * b0.z + a1.w * b0.w;
            acc[1][1] += a1.x * b1.x + a1.y * b1.y + a1.z * b1.z + a1.w * b1.w;
            acc[1][2] += a1.x * b2.x + a1.y * b2.y + a1.z * b2.z + a1.w * b2.w;
            acc[1][3] += a1.x * b3.x + a1.y * b3.y + a1.z * b3.z + a1.w * b3.w;
        }
        __syncthreads();
    }
    #pragma unroll
    for (int i = 0; i < 2; ++i) {
        int r = rbase + tm * 2 + i;
        #pragma unroll
        for (int jj = 0; jj < 4; ++jj) {
            int v = vbase + tn * 4 + jj;
            out[(size_t)r * VV + v] = acc[i][jj] + bg[v];
        }
    }
}

// ---------------------------------------------------------------------------
__global__ __launch_bounds__(256)
void logsoftmax_kernel(float* __restrict__ out)
{
    __shared__ float red[4];
    __shared__ float red2[4];
    const int tid = threadIdx.x;
    float* row = out + (size_t)blockIdx.x * VV;
    float m = -1e30f;
    for (int i = tid; i < VV; i += 256) m = fmaxf(m, row[i]);
    for (int off = 32; off; off >>= 1) m = fmaxf(m, __shfl_xor(m, off));
    if ((tid & 63) == 0) red[tid >> 6] = m;
    __syncthreads();
    m = fmaxf(fmaxf(red[0], red[1]), fmaxf(red[2], red[3]));
    float s = 0.f;
    for (int i = tid; i < VV; i += 256) s += expf(row[i] - m);
    for (int off = 32; off; off >>= 1) s += __shfl_xor(s, off);
    if ((tid & 63) == 0) red2[tid >> 6] = s;
    __syncthreads();
    s = red2[0] + red2[1] + red2[2] + red2[3];
    float lse = m + logf(s);
    for (int i = tid; i < VV; i += 256) row[i] = row[i] - lse;
}

// ---------------------------------------------------------------------------
extern "C" void kernel_launch(void* const* d_in, const int* in_sizes, int n_in,
                              void* d_out, int out_size, void* d_ws, size_t ws_size,
                              hipStream_t stream)
{
    (void)in_sizes; (void)n_in; (void)out_size; (void)ws_size;
    const int*   x    = (const int*)  d_in[0];
    const float* h0   = (const float*)d_in[1];
    const float* c0   = (const float*)d_in[2];
    const float* x_enc= (const float*)d_in[3];
    const float* emb  = (const float*)d_in[4];
    const float* Wih0 = (const float*)d_in[5];
    const float* Whh0 = (const float*)d_in[6];
    const float* bih0 = (const float*)d_in[7];
    const float* bhh0 = (const float*)d_in[8];
    const float* Wih1 = (const float*)d_in[9];
    const float* Whh1 = (const float*)d_in[10];
    const float* bih1 = (const float*)d_in[11];
    const float* bhh1 = (const float*)d_in[12];
    const float* Wa   = (const float*)d_in[13];
    const float* ba   = (const float*)d_in[14];
    const float* Wl   = (const float*)d_in[15];
    const float* bl   = (const float*)d_in[16];
    const float* Wg   = (const float*)d_in[17];
    const float* bg   = (const float*)d_in[18];
    float* out = (float*)d_out;
    float* scratch = (float*)d_out;   // overwritten by gen_gemm at the end

    float* ws    = (float*)d_ws;
    float* cst   = ws;                         // [2][32][1024]
    float* outs  = ws + WS_OUTS;               // [63][32][1024]
    unsigned* flags = (unsigned*)(ws + WS_FLAGS);

    float* xc0 = scratch + OXC0;
    float* xc1 = scratch + OXC1;
    float* zct = scratch + OZC;
    float* pe  = scratch + OPE;
    float* cb  = scratch + OCB;

    // ---- setup
    init_kernel2<<<256, 256, 0, stream>>>(h0, c0, cst, xc0, xc1, flags);
    embed_kernel2<<<TT * BB, 128, 0, stream>>>(x, emb, xc0);
    projenc_kernel<<<2048, 256, 0, stream>>>(x_enc, Wa, pe);
    cbias_kernel<<<2048, 64, 0, stream>>>(x_enc, ba, cb);

    // ---- recurrence: persistent kernel with custom barriers
    static int coopGrid = -2;
    if (coopGrid == -2) {
        int dev = 0; hipGetDevice(&dev);
        int coop = 0;
        hipDeviceGetAttribute(&coop, hipDeviceAttributeCooperativeLaunch, dev);
        if (!coop) coopGrid = 0;
        else {
            int occ = 0;
            if (hipOccupancyMaxActiveBlocksPerMultiprocessor(&occ, decoder_loop,
                    256, 0) != hipSuccess || occ < 1) occ = 0;
            int nCU = 256;
            hipDeviceProp_t prop;
            if (hipGetDeviceProperties(&prop, dev) == hipSuccess &&
                prop.multiProcessorCount > 0)
                nCU = prop.multiProcessorCount;
            int g = occ * nCU;
            if (g > 512) g = 512;
            coopGrid = g;
        }
    }

    bool done = false;
    if (coopGrid > 0) {
        void* args[] = {(void*)&Wih0, (void*)&Whh0, (void*)&bih0, (void*)&bhh0,
                        (void*)&Wih1, (void*)&Whh1, (void*)&bih1, (void*)&bhh1,
                        (void*)&Wl, (void*)&bl, (void*)&x_enc,
                        (void*)&scratch, (void*)&cst, (void*)&outs, (void*)&flags};
        hipError_t e = hipLaunchCooperativeKernel(decoder_loop, dim3(coopGrid),
                                                  dim3(256), args, 0u, stream);
        if (e == hipSuccess) done = true;
        else coopGrid = 0;
    }
    if (!done) {
        for (int t = 0; t < TT; ++t) {
            float* xc0t = xc0 + (size_t)t * BB * 2560;
            float* xc0n = xc0 + (size_t)(t + 1) * BB * 2560;
            float* xc1t = xc1 + (size_t)t * BB * 2048;
            float* xc1n = xc1 + (size_t)(t + 1) * BB * 2048;
            float* zc   = zct + (size_t)t * BB * 2048;
            k_lstm<<<512, 256, 0, stream>>>(Wih0, 1536, Whh0, bih0, bhh0,
                xc0t, 2560, cst, xc1t, 2048, 0, xc0n, 2560, 1536);
            k_lstm<<<512, 256, 0, stream>>>(Wih1, 1024, Whh1, bih1, bhh1,
                xc1t, 2048, cst + 32768, zc, 2048, 0, xc1n, 2048, 1024);
            k_attn<<<32, 256, 0, stream>>>(x_enc, pe, cb, zc);
            k_outlin<<<512, 256, 0, stream>>>(Wl, bl, zc,
                outs + (size_t)t * BB * HH, xc0n);
        }
    }

    // ---- generator + log-softmax
    gen_gemm_kernel<<<dim3(VV / 64, 2016 / 32), 256, 0, stream>>>(outs, Wg, bg, out);
    logsoftmax_kernel<<<2016, 256, 0, stream>>>(out);
}